// Round 8
// baseline (132.769 us; speedup 1.0000x reference)
//
#include <hip/hip_runtime.h>
#include <hip/hip_bf16.h>

// FEELModel: fp8 emb table + fused gathers (fp32 accum); TreeLSTM + sim head via bf16 MFMA.
// R8: 16B-lane gather (+wprep folded in), vectorized activations, 16-elem conv.
// B=512, L=64, Lq=128, D=M=512, 3M=1536, H=256, O=30

typedef __attribute__((ext_vector_type(8))) short short8;   // 8 bf16
typedef __attribute__((ext_vector_type(4))) float floatx4;  // MFMA C/D frag
typedef __attribute__((ext_vector_type(2))) float floatx2;

__device__ inline ushort f2bf(float f) {            // fp32 -> bf16 bits, RNE
    unsigned u = __float_as_uint(f);
    u += 0x7fffu + ((u >> 16) & 1u);
    return (ushort)(u >> 16);
}
__device__ inline float bf2f(ushort u) { return __uint_as_float((unsigned)u << 16); }
__device__ inline float sigm(float x) { return 1.0f / (1.0f + expf(-x)); }

#if defined(__has_builtin)
#if __has_builtin(__builtin_amdgcn_cvt_pk_f32_fp8) && __has_builtin(__builtin_amdgcn_cvt_pk_fp8_f32)
#define HW_FP8 1
#endif
#endif

#ifndef HW_FP8
__device__ inline unsigned enc1(float x) {          // manual e4m3fn encode, RNE, saturating
    float a = fabsf(x);
    unsigned s = (__float_as_uint(x) >> 31) << 7;
    unsigned b = __float_as_uint(a);
    unsigned uexp = b >> 23;
    if (uexp < 121) {
        int m = (int)(a * 512.0f + 0.5f);
        if (m >= 8) return s | 0x08u;
        return s | (unsigned)m;
    }
    b += 0x00080000u;
    unsigned e = b >> 23;
    if (e > 135u) return s | 0x7Eu;
    return s | ((e - 120u) << 3) | ((b >> 20) & 7u);
}
__device__ inline float dec1(unsigned v) {
    unsigned s = (v >> 7) & 1u, e = (v >> 3) & 15u, m = v & 7u;
    float r = e ? __uint_as_float(((e + 120u) << 23) | (m << 20))
                : (float)m * 0.001953125f;
    return s ? -r : r;
}
#endif

__device__ inline unsigned pk4(float a, float b, float c, float d) {
#ifdef HW_FP8
    int v = 0;
    v = __builtin_amdgcn_cvt_pk_fp8_f32(a, b, v, false);
    v = __builtin_amdgcn_cvt_pk_fp8_f32(c, d, v, true);
    return (unsigned)v;
#else
    return enc1(a) | (enc1(b) << 8) | (enc1(c) << 16) | (enc1(d) << 24);
#endif
}
__device__ inline void dec4_add(unsigned v, float* acc) {
#ifdef HW_FP8
    floatx2 p0 = __builtin_amdgcn_cvt_pk_f32_fp8(v, false);
    floatx2 p1 = __builtin_amdgcn_cvt_pk_f32_fp8(v, true);
    acc[0] += p0[0]; acc[1] += p0[1]; acc[2] += p1[0]; acc[3] += p1[1];
#else
    acc[0] += dec1(v & 255u); acc[1] += dec1((v >> 8) & 255u);
    acc[2] += dec1((v >> 16) & 255u); acc[3] += dec1(v >> 24);
#endif
}

#define GLD16(gp, sp)                                                        \
    __builtin_amdgcn_global_load_lds(                                        \
        (const __attribute__((address_space(1))) unsigned int*)(const void*)(gp), \
        (__attribute__((address_space(3))) unsigned int*)(void*)(sp), 16, 0, 0)

#define FP8_SCALE 64.0f

// ---------------- conv: emb fp32 -> fp8 (x64 scale), 16 elems/thread ----------------
__global__ __launch_bounds__(256) void conv_kernel(const float* __restrict__ emb,
                                                   unsigned char* __restrict__ emb8) {
    size_t i = ((size_t)blockIdx.x * 256 + threadIdx.x) * 16;
    float4 a = *(const float4*)(emb + i);
    float4 b = *(const float4*)(emb + i + 4);
    float4 c = *(const float4*)(emb + i + 8);
    float4 d = *(const float4*)(emb + i + 12);
    uint4 o;
    o.x = pk4(a.x * FP8_SCALE, a.y * FP8_SCALE, a.z * FP8_SCALE, a.w * FP8_SCALE);
    o.y = pk4(b.x * FP8_SCALE, b.y * FP8_SCALE, b.z * FP8_SCALE, b.w * FP8_SCALE);
    o.z = pk4(c.x * FP8_SCALE, c.y * FP8_SCALE, c.z * FP8_SCALE, c.w * FP8_SCALE);
    o.w = pk4(d.x * FP8_SCALE, d.y * FP8_SCALE, d.z * FP8_SCALE, d.w * FP8_SCALE);
    *(uint4*)(emb8 + i) = o;
}

// ---------------- gather (16B/lane) + weight prep, one launch ----------------
// blocks [0,3584): attr pools (64 tok) -> fp32 pools ; [3584,9728): tree pools (32 tok)
// [9728,11905): weight transposes + wsum (independent of emb8)
// gather: c = tid&31 (16B chunk = dims [c*16,c*16+16)), g = tid>>5 (8 token groups)
__global__ __launch_bounds__(256) void gather_wprep_kernel(
    const int* __restrict__ q_v,
    const int* __restrict__ qa0, const int* __restrict__ na0,
    const int* __restrict__ qa1, const int* __restrict__ na1,
    const int* __restrict__ qa2, const int* __restrict__ na2,
    const int* __restrict__ query, const int* __restrict__ pos, const int* __restrict__ neg,
    const unsigned char* __restrict__ emb8,
    float* __restrict__ pools, ushort* __restrict__ Xleaf, ushort* __restrict__ XR,
    const float* __restrict__ Wioux, const float* __restrict__ Wiouh,
    const float* __restrict__ Wfh, const float* __restrict__ Wfx,
    const float* __restrict__ Wwh, const float* __restrict__ Wwp,
    const float* __restrict__ bwp,
    ushort* __restrict__ Wcat_t, ushort* __restrict__ Wfh_t,
    ushort* __restrict__ Wfx_t, ushort* __restrict__ Wwh_t,
    float* __restrict__ wsum) {
    __shared__ alignas(16) char smem_u[16384];
    int blk = blockIdx.x, tid = threadIdx.x;

    if (blk < 9728) {   // ---- gather ----
        float* sm = (float*)smem_u;             // [256][16]
        int c = tid & 31, g = tid >> 5;
        float acc[16] = {};
        if (blk < 3584) {
            int s = blk >> 9, b = blk & 511;
            const int* aptr[7] = {q_v, qa0, na0, qa1, na1, qa2, na2};
            const int* ids = aptr[s] + b * 64 + g * 8;
            uint4 v[8];
#pragma unroll
            for (int k = 0; k < 8; ++k)
                v[k] = *(const uint4*)(emb8 + (size_t)ids[k] * 512 + c * 16);
#pragma unroll
            for (int k = 0; k < 8; ++k) {
                dec4_add(v[k].x, acc); dec4_add(v[k].y, acc + 4);
                dec4_add(v[k].z, acc + 8); dec4_add(v[k].w, acc + 12);
            }
#pragma unroll
            for (int j = 0; j < 4; ++j)
                *(float4*)(sm + tid * 16 + j * 4) = *(float4*)(acc + j * 4);
            __syncthreads();
            if (tid < 32) {
#pragma unroll
                for (int gg = 1; gg < 8; ++gg)
#pragma unroll
                    for (int j = 0; j < 16; ++j) acc[j] += sm[(gg * 32 + tid) * 16 + j];
                const float sc = 1.0f / (64.0f * FP8_SCALE);
                float* dst = pools + ((size_t)s * 512 + b) * 512 + tid * 16;
#pragma unroll
                for (int j = 0; j < 4; ++j)
                    *(float4*)(dst + j * 4) = make_float4(acc[j*4] * sc, acc[j*4+1] * sc,
                                                          acc[j*4+2] * sc, acc[j*4+3] * sc);
            }
        } else {
            int idx = blk - 3584;
            int t = idx >> 11, rem = idx & 2047, b = rem >> 2, node = rem & 3;
            const int* sptr[3] = {query, pos, neg};
            const int* ids = sptr[t] + b * 128 + node * 32 + g * 4;
            uint4 v[4];
#pragma unroll
            for (int k = 0; k < 4; ++k)
                v[k] = *(const uint4*)(emb8 + (size_t)ids[k] * 512 + c * 16);
#pragma unroll
            for (int k = 0; k < 4; ++k) {
                dec4_add(v[k].x, acc); dec4_add(v[k].y, acc + 4);
                dec4_add(v[k].z, acc + 8); dec4_add(v[k].w, acc + 12);
            }
#pragma unroll
            for (int j = 0; j < 4; ++j)
                *(float4*)(sm + tid * 16 + j * 4) = *(float4*)(acc + j * 4);
            __syncthreads();
            if (tid < 32) {
#pragma unroll
                for (int gg = 1; gg < 8; ++gg)
#pragma unroll
                    for (int j = 0; j < 16; ++j) acc[j] += sm[(gg * 32 + tid) * 16 + j];
                const float sc = 1.0f / (32.0f * FP8_SCALE);
                short8 o0, o1;
#pragma unroll
                for (int j = 0; j < 8; ++j) {
                    o0[j] = (short)f2bf(acc[j] * sc);
                    o1[j] = (short)f2bf(acc[j + 8] * sc);
                }
                if (node < 3) {
                    size_t r = ((size_t)(t * 512 + b)) * 3 + node;
                    *(short8*)(Xleaf + r * 512 + tid * 16) = o0;
                    *(short8*)(Xleaf + r * 512 + tid * 16 + 8) = o1;
                } else {
                    size_t r = (size_t)(t * 512 + b);
                    *(short8*)(XR + r * 1024 + tid * 16) = o0;
                    *(short8*)(XR + r * 1024 + tid * 16 + 8) = o1;
                }
            }
        }
        return;
    }
    // ---- weight prep ----
    float* tt = (float*)smem_u;                 // [32][33]
    int wblk = blk - 9728;
    int tx = tid & 31, ty = tid >> 5;
    if (wblk < 1536) {  // Wcat: logical [1024][1536] -> Wcat_t[1536][1024]
        int k0 = (wblk & 31) * 32, n0 = (wblk >> 5) * 32;
#pragma unroll
        for (int r = 0; r < 4; ++r) {
            int k = k0 + ty + r * 8;
            const float* s = (k < 512) ? Wioux + (size_t)k * 1536
                                       : Wiouh + (size_t)(k - 512) * 1536;
            tt[(ty + r * 8) * 33 + tx] = s[n0 + tx];
        }
        __syncthreads();
#pragma unroll
        for (int r = 0; r < 4; ++r)
            Wcat_t[(size_t)(n0 + ty + r * 8) * 1024 + k0 + tx] = f2bf(tt[tx * 33 + ty + r * 8]);
        return;
    }
    if (wblk < 2176) {  // K=512 transposes -> [N][512]
        const float* W; ushort* Wt; int idx, ncols;
        if (wblk < 1792)      { idx = wblk - 1536; W = Wfh; Wt = Wfh_t; ncols = 512; }
        else if (wblk < 2048) { idx = wblk - 1792; W = Wfx; Wt = Wfx_t; ncols = 512; }
        else                  { idx = wblk - 2048; W = Wwh; Wt = Wwh_t; ncols = 256; }
        int nt_count = ncols >> 5;
        int k0 = (idx / nt_count) * 32, n0 = (idx % nt_count) * 32;
#pragma unroll
        for (int r = 0; r < 4; ++r)
            tt[(ty + r * 8) * 33 + tx] = W[(size_t)(k0 + ty + r * 8) * ncols + n0 + tx];
        __syncthreads();
#pragma unroll
        for (int r = 0; r < 4; ++r)
            Wt[(size_t)(n0 + ty + r * 8) * 512 + k0 + tx] = f2bf(tt[tx * 33 + ty + r * 8]);
        return;
    }
    {   // wsum
        float s = 0.f;
        for (int o = 0; o < 30; ++o) s += Wwp[tid * 30 + o];
        wsum[tid] = s;
        if (tid == 0) {
            float t = 0.f;
            for (int o = 0; o < 30; ++o) t += bwp[o];
            wsum[256] = t;
        }
    }
}

// ---------------- bf16 MFMA GEMM body (double-buffered, swizzled LDS) ----------------
__device__ inline void cstore(float* C, size_t idx, float v)  { C[idx] = v; }
__device__ inline void cstore(ushort* C, size_t idx, float v) { C[idx] = f2bf(v); }

template <typename OutT>
__device__ __forceinline__ void gemm_body(const ushort* __restrict__ A, int lda,
                                          const ushort* __restrict__ Bt, int ldb,
                                          OutT* __restrict__ C, int ldc, int K,
                                          int bx, int by, ushort* sA, ushort* sB) {
    int tid = threadIdx.x;
    int m0 = bx * 128, n0 = by * 128;
    int w = tid >> 6, lane = tid & 63;
    int wm = (w >> 1) * 64, wn = (w & 1) * 64;
    int l15 = lane & 15, g = lane >> 4;
    int srow = tid >> 2;
    int csw = (((tid & 3) ^ ((tid >> 3) & 3))) * 8;   // swizzled source chunk (elems)
    int crd = (g ^ ((l15 >> 1) & 3)) * 8;             // swizzled read chunk (elems)

    const ushort* Ag0 = A + (size_t)(m0 + srow) * lda + csw;
    const ushort* Ag1 = A + (size_t)(m0 + srow + 64) * lda + csw;
    const ushort* Bg0 = Bt + (size_t)(n0 + srow) * ldb + csw;
    const ushort* Bg1 = Bt + (size_t)(n0 + srow + 64) * ldb + csw;

    floatx4 acc[4][4] = {};

    auto stage = [&](int buf, int kb) {
        ushort* dA = sA + buf * 4096;
        ushort* dB = sB + buf * 4096;
        GLD16(Ag0 + kb, dA + w * 512);
        GLD16(Ag1 + kb, dA + 2048 + w * 512);
        GLD16(Bg0 + kb, dB + w * 512);
        GLD16(Bg1 + kb, dB + 2048 + w * 512);
    };

    stage(0, 0);
    __syncthreads();
    int cur = 0;
    for (int kb = 0; kb < K; kb += 32) {
        if (kb + 32 < K) stage(cur ^ 1, kb + 32);
        const ushort* bA = sA + cur * 4096;
        const ushort* bB = sB + cur * 4096;
        short8 af[4], bf[4];
#pragma unroll
        for (int f = 0; f < 4; ++f) {
            af[f] = *(const short8*)(bA + (wm + f * 16 + l15) * 32 + crd);
            bf[f] = *(const short8*)(bB + (wn + f * 16 + l15) * 32 + crd);
        }
#pragma unroll
        for (int i = 0; i < 4; ++i)
#pragma unroll
            for (int j = 0; j < 4; ++j)
                acc[i][j] = __builtin_amdgcn_mfma_f32_16x16x32_bf16(af[i], bf[j], acc[i][j], 0, 0, 0);
        __syncthreads();
        cur ^= 1;
    }
    // C/D layout (HW-verified): col = lane&15, row = 4*(lane>>4)+reg
#pragma unroll
    for (int i = 0; i < 4; ++i)
#pragma unroll
        for (int j = 0; j < 4; ++j) {
            int row = m0 + wm + i * 16 + g * 4;
            int col = n0 + wn + j * 16 + l15;
#pragma unroll
            for (int r = 0; r < 4; ++r)
                cstore(C, (size_t)(row + r) * ldc + col, acc[i][j][r]);
        }
}

// G1 (leaf IOU, 432 blocks) + dots (512 blocks) in one launch
__global__ __launch_bounds__(256) void g1_dots_kernel(
    const ushort* __restrict__ Xleaf, const ushort* __restrict__ Wcat_t,
    ushort* __restrict__ IOU_l,
    const float* __restrict__ pools, float* __restrict__ lossv) {
    __shared__ alignas(16) ushort sA[8192];
    __shared__ alignas(16) ushort sB[8192];
    __shared__ float red[6][4];
    int blk = blockIdx.x, tid = threadIdx.x;
    if (blk < 432) {
        gemm_body(Xleaf, 512, Wcat_t, 1024, IOU_l, 1536, 512, blk % 36, blk / 36, sA, sB);
        return;
    }
    int b = blk - 432;
    const float* pq = pools + (size_t)b * 512;
    float q0 = pq[tid], q1 = pq[tid + 256];
    float d[6];
#pragma unroll
    for (int a = 0; a < 6; ++a) {
        const float* pa = pools + ((size_t)(a + 1) * 512 + b) * 512;
        d[a] = q0 * pa[tid] + q1 * pa[tid + 256];
    }
    int lane = tid & 63, wid = tid >> 6;
#pragma unroll
    for (int a = 0; a < 6; ++a) {
        float v = d[a];
        for (int off = 32; off; off >>= 1) v += __shfl_down(v, off);
        if (lane == 0) red[a][wid] = v;
    }
    __syncthreads();
    if (tid == 0) {
        float l = 0.f;
#pragma unroll
        for (int i = 0; i < 3; ++i) {
            float dq = red[2*i][0] + red[2*i][1] + red[2*i][2] + red[2*i][3];
            float dn = red[2*i+1][0] + red[2*i+1][1] + red[2*i+1][2] + red[2*i+1][3];
            l += fmaxf(0.f, 1.f - dq + dn);
        }
        lossv[b] = l;
    }
}

// G4 (IOU_r, K=1024, blocks 0-143) + G2 (FH, 144-287) + G3 (FX, 288-335)
__global__ __launch_bounds__(256) void gemm3_kernel(
    const ushort* __restrict__ h_l, const ushort* __restrict__ XR,
    const ushort* __restrict__ Wfh_t, const ushort* __restrict__ Wfx_t,
    const ushort* __restrict__ Wcat_t,
    ushort* __restrict__ FH, ushort* __restrict__ FX, ushort* __restrict__ IOU_r) {
    __shared__ alignas(16) ushort sA[8192];
    __shared__ alignas(16) ushort sB[8192];
    int r = blockIdx.x;
    if (r < 144)      gemm_body(XR, 1024, Wcat_t, 1024, IOU_r, 1536, 1024, r % 12, r / 12, sA, sB);
    else if (r < 288) { int q = r - 144; gemm_body(h_l, 512, Wfh_t, 512, FH, 512, 512, q % 36, q / 36, sA, sB); }
    else              { int q = r - 288; gemm_body(XR, 1024, Wfx_t, 512, FX, 512, 512, q % 12, q / 12, sA, sB); }
}

// sim GEMM: S[1024,256] = P @ Wwh, P rows built on the fly from c_root.
__global__ __launch_bounds__(256) void gemm_sim_kernel(
    const float* __restrict__ c_root, const ushort* __restrict__ Wwh_t,
    float* __restrict__ S) {
    __shared__ alignas(16) ushort sA[8192];
    __shared__ alignas(16) ushort sB[8192];
    int tid = threadIdx.x;
    int bx = blockIdx.x & 7, by = blockIdx.x >> 3;
    int m0 = bx * 128, n0 = by * 128;
    int w = tid >> 6, lane = tid & 63;
    int wm = (w >> 1) * 64, wn = (w & 1) * 64;
    int l15 = lane & 15, g = lane >> 4;
    int srow = tid >> 2;
    int csw = (((tid & 3) ^ ((tid >> 3) & 3))) * 8;
    int crd = (g ^ ((l15 >> 1) & 3)) * 8;

    const ushort* Bg0 = Wwh_t + (size_t)(n0 + srow) * 512 + csw;
    const ushort* Bg1 = Wwh_t + (size_t)(n0 + srow + 64) * 512 + csw;

    floatx4 acc[4][4] = {};

    auto stage = [&](int buf, int kb) {
        ushort* dA = sA + buf * 4096;
        ushort* dB = sB + buf * 4096;
        GLD16(Bg0 + kb, dB + w * 512);
        GLD16(Bg1 + kb, dB + 2048 + w * 512);
#pragma unroll
        for (int half = 0; half < 2; ++half) {
            int gr = m0 + srow + half * 64;
            int b = gr & 511, which = gr >> 9;
            const float* qrow = c_root + (size_t)b * 512 + kb + csw;
            const float* orow = c_root + ((size_t)(which + 1) * 512 + b) * 512 + kb + csw;
            float4 q0 = *(const float4*)qrow, q1 = *(const float4*)(qrow + 4);
            float4 o0 = *(const float4*)orow, o1 = *(const float4*)(orow + 4);
            short8 pv;
            pv[0] = (short)f2bf(q0.x * o0.x); pv[1] = (short)f2bf(q0.y * o0.y);
            pv[2] = (short)f2bf(q0.z * o0.z); pv[3] = (short)f2bf(q0.w * o0.w);
            pv[4] = (short)f2bf(q1.x * o1.x); pv[5] = (short)f2bf(q1.y * o1.y);
            pv[6] = (short)f2bf(q1.z * o1.z); pv[7] = (short)f2bf(q1.w * o1.w);
            *(short8*)(dA + (srow + half * 64) * 32 + (tid & 3) * 8) = pv;
        }
    };

    stage(0, 0);
    __syncthreads();
    int cur = 0;
    for (int kb = 0; kb < 512; kb += 32) {
        if (kb + 32 < 512) stage(cur ^ 1, kb + 32);
        const ushort* bA = sA + cur * 4096;
        const ushort* bB = sB + cur * 4096;
        short8 af[4], bf[4];
#pragma unroll
        for (int f = 0; f < 4; ++f) {
            af[f] = *(const short8*)(bA + (wm + f * 16 + l15) * 32 + crd);
            bf[f] = *(const short8*)(bB + (wn + f * 16 + l15) * 32 + crd);
        }
#pragma unroll
        for (int i = 0; i < 4; ++i)
#pragma unroll
            for (int j = 0; j < 4; ++j)
                acc[i][j] = __builtin_amdgcn_mfma_f32_16x16x32_bf16(af[i], bf[j], acc[i][j], 0, 0, 0);
        __syncthreads();
        cur ^= 1;
    }
#pragma unroll
    for (int i = 0; i < 4; ++i)
#pragma unroll
        for (int j = 0; j < 4; ++j) {
            int row = m0 + wm + i * 16 + g * 4;
            int col = n0 + wn + j * 16 + l15;
#pragma unroll
            for (int r = 0; r < 4; ++r)
                S[(size_t)(row + r) * 256 + col] = acc[i][j][r];
        }
}

// ---------------- TreeLSTM epilogues (vectorized: 4 trees/block, 64 lanes/tree) ----------------

__global__ __launch_bounds__(256) void leaf_act_kernel(
    const ushort* __restrict__ IOU_l, const float* __restrict__ bioux,
    const float* __restrict__ biouh, ushort* __restrict__ c_l,
    ushort* __restrict__ h_l, ushort* __restrict__ XR) {
    int tb = blockIdx.x * 4 + (threadIdx.x >> 6);
    int d0 = (threadIdx.x & 63) * 8;
    float bi[8], bo[8], bu[8];
#pragma unroll
    for (int gate = 0; gate < 3; ++gate) {
        float* dst = gate == 0 ? bi : (gate == 1 ? bo : bu);
        int m = gate * 512 + d0;
        float4 x0 = *(const float4*)(bioux + m), x1 = *(const float4*)(bioux + m + 4);
        float4 h0 = *(const float4*)(biouh + m), h1 = *(const float4*)(biouh + m + 4);
        dst[0] = x0.x + h0.x; dst[1] = x0.y + h0.y; dst[2] = x0.z + h0.z; dst[3] = x0.w + h0.w;
        dst[4] = x1.x + h1.x; dst[5] = x1.y + h1.y; dst[6] = x1.z + h1.z; dst[7] = x1.w + h1.w;
    }
    float hs[8] = {};
#pragma unroll
    for (int leaf = 0; leaf < 3; ++leaf) {
        size_t r = (size_t)tb * 3 + leaf;
        short8 vi = *(const short8*)(IOU_l + r * 1536 + d0);
        short8 vo = *(const short8*)(IOU_l + r * 1536 + 512 + d0);
        short8 vu = *(const short8*)(IOU_l + r * 1536 + 1024 + d0);
        short8 cb, hb;
#pragma unroll
        for (int j = 0; j < 8; ++j) {
            float iv = sigm(bf2f((ushort)vi[j]) + bi[j]);
            float ov = sigm(bf2f((ushort)vo[j]) + bo[j]);
            float uv = tanhf(bf2f((ushort)vu[j]) + bu[j]);
            float cc = iv * uv;
            cb[j] = (short)f2bf(cc);
            float hh = ov * tanhf(cc);
            hb[j] = (short)f2bf(hh);
            hs[j] += hh;
        }
        *(short8*)(c_l + r * 512 + d0) = cb;
        *(short8*)(h_l + r * 512 + d0) = hb;
    }
    short8 hsb;
#pragma unroll
    for (int j = 0; j < 8; ++j) hsb[j] = (short)f2bf(hs[j]);
    *(short8*)(XR + (size_t)tb * 1024 + 512 + d0) = hsb;
}

__global__ __launch_bounds__(256) void root_act_kernel(
    const ushort* __restrict__ IOU_r, const ushort* __restrict__ FH,
    const ushort* __restrict__ FX, const ushort* __restrict__ c_l,
    const float* __restrict__ bioux, const float* __restrict__ biouh,
    const float* __restrict__ bfx, const float* __restrict__ bfh,
    float* __restrict__ c_root) {
    int r = blockIdx.x * 4 + (threadIdx.x >> 6);
    int d0 = (threadIdx.x & 63) * 8;
    float bi[8], bu[8], bfxv[8], bfhv[8];
    {
        float4 x0 = *(const float4*)(bioux + d0), x1 = *(const float4*)(bioux + d0 + 4);
        float4 h0 = *(const float4*)(biouh + d0), h1 = *(const float4*)(biouh + d0 + 4);
        bi[0] = x0.x + h0.x; bi[1] = x0.y + h0.y; bi[2] = x0.z + h0.z; bi[3] = x0.w + h0.w;
        bi[4] = x1.x + h1.x; bi[5] = x1.y + h1.y; bi[6] = x1.z + h1.z; bi[7] = x1.w + h1.w;
        float4 u0 = *(const float4*)(bioux + 1024 + d0), u1 = *(const float4*)(bioux + 1024 + d0 + 4);
        float4 v0 = *(const float4*)(biouh + 1024 + d0), v1 = *(const float4*)(biouh + 1024 + d0 + 4);
        bu[0] = u0.x + v0.x; bu[1] = u0.y + v0.y; bu[2] = u0.z + v0.z; bu[3] = u0.w + v0.w;
        bu[4] = u1.x + v1.x; bu[5] = u1.y + v1.y; bu[6] = u1.z + v1.z; bu[7] = u1.w + v1.w;
        float4 f0 = *(const float4*)(bfx + d0), f1 = *(const float4*)(bfx + d0 + 4);
        bfxv[0] = f0.x; bfxv[1] = f0.y; bfxv[2] = f0.z; bfxv[3] = f0.w;
        bfxv[4] = f1.x; bfxv[5] = f1.y; bfxv[6] = f1.z; bfxv[7] = f1.w;
        float4 g0 = *(const float4*)(bfh + d0), g1 = *(const float4*)(bfh + d0 + 4);
        bfhv[0] = g0.x; bfhv[1] = g0.y; bfhv[2] = g0.z; bfhv[3] = g0.w;
        bfhv[4] = g1.x; bfhv[5] = g1.y; bfhv[6] = g1.z; bfhv[7] = g1.w;
    }
    short8 vi = *(const short8*)(IOU_r + (size_t)r * 1536 + d0);
    short8 vu = *(const short8*)(IOU_r + (size_t)r * 1536 + 1024 + d0);
    short8 vfx = *(const short8*)(FX + (size_t)r * 512 + d0);
    float c[8], fx[8];
#pragma unroll
    for (int j = 0; j < 8; ++j) {
        float iv = sigm(bf2f((ushort)vi[j]) + bi[j]);
        float uv = tanhf(bf2f((ushort)vu[j]) + bu[j]);
        fx[j] = bf2f((ushort)vfx[j]) + bfxv[j];
        c[j] = iv * uv;
    }
#pragma unroll
    for (int k = 0; k < 3; ++k) {
        size_t rr = ((size_t)r * 3 + k) * 512 + d0;
        short8 vfh = *(const short8*)(FH + rr);
        short8 vcl = *(const short8*)(c_l + rr);
#pragma unroll
        for (int j = 0; j < 8; ++j) {
            float f = sigm(bf2f((ushort)vfh[j]) + bfhv[j] + fx[j]);
            c[j] += f * bf2f((ushort)vcl[j]);
        }
    }
    *(float4*)(c_root + (size_t)r * 512 + d0)     = make_float4(c[0], c[1], c[2], c[3]);
    *(float4*)(c_root + (size_t)r * 512 + d0 + 4) = make_float4(c[4], c[5], c[6], c[7]);
}

__global__ __launch_bounds__(256) void final_kernel(
    const float* __restrict__ S, const float* __restrict__ bwh,
    const float* __restrict__ wsum, const float* __restrict__ loss,
    float* __restrict__ out) {
    int b = blockIdx.x, tid = threadIdx.x;
    float w = wsum[tid];
    float bw = bwh[tid];
    float va = sigm(S[(size_t)b * 256 + tid] + bw) * w;
    float vb = sigm(S[(size_t)(512 + b) * 256 + tid] + bw) * w;
    int lane = tid & 63, wid = tid >> 6;
    for (int off = 32; off; off >>= 1) {
        va += __shfl_down(va, off);
        vb += __shfl_down(vb, off);
    }
    __shared__ float ra[4], rb[4];
    if (lane == 0) { ra[wid] = va; rb[wid] = vb; }
    __syncthreads();
    if (tid == 0) {
        float a  = ra[0] + ra[1] + ra[2] + ra[3] + wsum[256];
        float bb = rb[0] + rb[1] + rb[2] + rb[3] + wsum[256];
        out[b] = loss[b] + fmaxf(0.f, 1.f - a + bb);
    }
}

// ---------------- launch ----------------

extern "C" void kernel_launch(void* const* d_in, const int* in_sizes, int n_in,
                              void* d_out, int out_size, void* d_ws, size_t ws_size,
                              hipStream_t stream) {
    const int* q_v   = (const int*)d_in[0];
    const int* q_a0  = (const int*)d_in[1];
    const int* n_a0  = (const int*)d_in[2];
    const int* q_a1  = (const int*)d_in[3];
    const int* n_a1  = (const int*)d_in[4];
    const int* q_a2  = (const int*)d_in[5];
    const int* n_a2  = (const int*)d_in[6];
    const int* query = (const int*)d_in[7];
    const int* pos   = (const int*)d_in[8];
    const int* neg   = (const int*)d_in[9];
    const float* emb   = (const float*)d_in[10];
    const float* Wioux = (const float*)d_in[11];
    const float* bioux = (const float*)d_in[12];
    const float* Wiouh = (const float*)d_in[13];
    const float* biouh = (const float*)d_in[14];
    const float* Wfx   = (const float*)d_in[15];
    const float* bfx   = (const float*)d_in[16];
    const float* Wfh   = (const float*)d_in[17];
    const float* bfh   = (const float*)d_in[18];
    const float* Wwh   = (const float*)d_in[19];
    const float* bwh   = (const float*)d_in[20];
    const float* Wwp   = (const float*)d_in[21];
    const float* bwp   = (const float*)d_in[22];
    float* out = (float*)d_out;

    char* w = (char*)d_ws;
    size_t off = 0;
    auto alloc = [&](size_t bytes) -> void* {
        void* p = (void*)(w + off);
        off = (off + bytes + 255) & ~(size_t)255;
        return p;
    };
    // ---- persistent region ----
    ushort* Wcat_t = (ushort*)alloc((size_t)1536 * 1024 * 2);
    ushort* Wfh_t  = (ushort*)alloc((size_t)512 * 512 * 2);
    ushort* Wfx_t  = (ushort*)alloc((size_t)512 * 512 * 2);
    ushort* Wwh_t  = (ushort*)alloc((size_t)256 * 512 * 2);
    float*  wsum   = (float*) alloc(257 * 4);
    float*  lossv  = (float*) alloc(512 * 4);
    ushort* Xleaf  = (ushort*)alloc((size_t)4608 * 512 * 2);
    ushort* XR     = (ushort*)alloc((size_t)1536 * 1024 * 2);
    // ---- aliased region: phase1 (emb8, pools) then phase2 (GEMM temporaries) ----
    size_t xbase = off;
    unsigned char* emb8 = (unsigned char*)alloc((size_t)50000 * 512);
    float* pools        = (float*)        alloc((size_t)7 * 512 * 512 * 4);
    off = xbase;   // rewind: safe by ordering (emb8 dead after gather; pools dead after dots)
    ushort* IOU_l  = (ushort*)alloc((size_t)4608 * 1536 * 2);
    ushort* c_l    = (ushort*)alloc((size_t)4608 * 512 * 2);
    ushort* h_l    = (ushort*)alloc((size_t)4608 * 512 * 2);
    ushort* FH     = (ushort*)alloc((size_t)4608 * 512 * 2);
    ushort* FX     = (ushort*)alloc((size_t)1536 * 512 * 2);
    ushort* IOU_r  = (ushort*)alloc((size_t)1536 * 1536 * 2);
    float*  c_root = (float*) alloc((size_t)1536 * 512 * 4);
    float*  S      = (float*) alloc((size_t)1024 * 256 * 4);

    conv_kernel<<<6250, 256, 0, stream>>>(emb, emb8);
    gather_wprep_kernel<<<11905, 256, 0, stream>>>(q_v, q_a0, n_a0, q_a1, n_a1, q_a2, n_a2,
                                                   query, pos, neg, emb8, pools, Xleaf, XR,
                                                   Wioux, Wiouh, Wfh, Wfx, Wwh, Wwp, bwp,
                                                   Wcat_t, Wfh_t, Wfx_t, Wwh_t, wsum);
    g1_dots_kernel<<<944, 256, 0, stream>>>(Xleaf, Wcat_t, IOU_l, pools, lossv);
    leaf_act_kernel<<<384, 256, 0, stream>>>(IOU_l, bioux, biouh, c_l, h_l, XR);
    gemm3_kernel<<<336, 256, 0, stream>>>(h_l, XR, Wfh_t, Wfx_t, Wcat_t, FH, FX, IOU_r);
    root_act_kernel<<<384, 256, 0, stream>>>(IOU_r, FH, FX, c_l, bioux, biouh, bfx, bfh, c_root);
    gemm_sim_kernel<<<16, 256, 0, stream>>>(c_root, Wwh_t, S);
    final_kernel<<<512, 256, 0, stream>>>(S, bwh, wsum, lossv, out);
}

// Round 9
// 127.399 us; speedup vs baseline: 1.0421x; 1.0421x over previous
//
#include <hip/hip_runtime.h>
#include <hip/hip_bf16.h>

// FEELModel: fp8 emb table + fused gathers (fp32 accum); TreeLSTM + sim head via bf16 MFMA.
// R9 = R7 proven structure (prep_all + 8B/lane gather, tid<64 reduce) + R8's vectorized
// activations. GEMMs double-buffered with chunk-XOR swizzle (neutral, retained).
// B=512, L=64, Lq=128, D=M=512, 3M=1536, H=256, O=30

typedef __attribute__((ext_vector_type(8))) short short8;   // 8 bf16
typedef __attribute__((ext_vector_type(4))) float floatx4;  // MFMA C/D frag
typedef __attribute__((ext_vector_type(2))) float floatx2;

__device__ inline ushort f2bf(float f) {            // fp32 -> bf16 bits, RNE
    unsigned u = __float_as_uint(f);
    u += 0x7fffu + ((u >> 16) & 1u);
    return (ushort)(u >> 16);
}
__device__ inline float bf2f(ushort u) { return __uint_as_float((unsigned)u << 16); }
__device__ inline float sigm(float x) { return 1.0f / (1.0f + expf(-x)); }

#if defined(__has_builtin)
#if __has_builtin(__builtin_amdgcn_cvt_pk_f32_fp8) && __has_builtin(__builtin_amdgcn_cvt_pk_fp8_f32)
#define HW_FP8 1
#endif
#endif

#ifndef HW_FP8
__device__ inline unsigned enc1(float x) {          // manual e4m3fn encode, RNE, saturating
    float a = fabsf(x);
    unsigned s = (__float_as_uint(x) >> 31) << 7;
    unsigned b = __float_as_uint(a);
    unsigned uexp = b >> 23;
    if (uexp < 121) {
        int m = (int)(a * 512.0f + 0.5f);
        if (m >= 8) return s | 0x08u;
        return s | (unsigned)m;
    }
    b += 0x00080000u;
    unsigned e = b >> 23;
    if (e > 135u) return s | 0x7Eu;
    return s | ((e - 120u) << 3) | ((b >> 20) & 7u);
}
__device__ inline float dec1(unsigned v) {
    unsigned s = (v >> 7) & 1u, e = (v >> 3) & 15u, m = v & 7u;
    float r = e ? __uint_as_float(((e + 120u) << 23) | (m << 20))
                : (float)m * 0.001953125f;
    return s ? -r : r;
}
#endif

__device__ inline unsigned pk4(float a, float b, float c, float d) {
#ifdef HW_FP8
    int v = 0;
    v = __builtin_amdgcn_cvt_pk_fp8_f32(a, b, v, false);
    v = __builtin_amdgcn_cvt_pk_fp8_f32(c, d, v, true);
    return (unsigned)v;
#else
    return enc1(a) | (enc1(b) << 8) | (enc1(c) << 16) | (enc1(d) << 24);
#endif
}
__device__ inline void dec4_add(unsigned v, float* acc) {
#ifdef HW_FP8
    floatx2 p0 = __builtin_amdgcn_cvt_pk_f32_fp8(v, false);
    floatx2 p1 = __builtin_amdgcn_cvt_pk_f32_fp8(v, true);
    acc[0] += p0[0]; acc[1] += p0[1]; acc[2] += p1[0]; acc[3] += p1[1];
#else
    acc[0] += dec1(v & 255u); acc[1] += dec1((v >> 8) & 255u);
    acc[2] += dec1((v >> 16) & 255u); acc[3] += dec1(v >> 24);
#endif
}

#define GLD16(gp, sp)                                                        \
    __builtin_amdgcn_global_load_lds(                                        \
        (const __attribute__((address_space(1))) unsigned int*)(const void*)(gp), \
        (__attribute__((address_space(3))) unsigned int*)(void*)(sp), 16, 0, 0)

#define FP8_SCALE 64.0f

// ---------------- mega prep: emb->fp8, coalesced transposes, wsum ----------------
__global__ __launch_bounds__(256) void prep_all_kernel(
    const float* __restrict__ emb, unsigned char* __restrict__ emb8,
    const float* __restrict__ Wioux, const float* __restrict__ Wiouh,
    const float* __restrict__ Wfh, const float* __restrict__ Wfx,
    const float* __restrict__ Wwh, const float* __restrict__ Wwp,
    const float* __restrict__ bwp,
    ushort* __restrict__ Wcat_t, ushort* __restrict__ Wfh_t,
    ushort* __restrict__ Wfx_t, ushort* __restrict__ Wwh_t,
    float* __restrict__ wsum) {
    __shared__ float tt[32][33];
    int blk = blockIdx.x, tid = threadIdx.x;
    if (blk < 12500) {
        size_t i = ((size_t)blk * 256 + tid) * 8;
        float4 a = *(const float4*)(emb + i);
        float4 b = *(const float4*)(emb + i + 4);
        uint2 o;
        o.x = pk4(a.x * FP8_SCALE, a.y * FP8_SCALE, a.z * FP8_SCALE, a.w * FP8_SCALE);
        o.y = pk4(b.x * FP8_SCALE, b.y * FP8_SCALE, b.z * FP8_SCALE, b.w * FP8_SCALE);
        *(uint2*)(emb8 + i) = o;
        return;
    }
    int tx = tid & 31, ty = tid >> 5;
    if (blk < 14036) {  // Wcat: logical [1024][1536] -> Wcat_t[1536][1024]
        int idx = blk - 12500;
        int k0 = (idx & 31) * 32, n0 = (idx >> 5) * 32;
#pragma unroll
        for (int r = 0; r < 4; ++r) {
            int k = k0 + ty + r * 8;
            const float* s = (k < 512) ? Wioux + (size_t)k * 1536
                                       : Wiouh + (size_t)(k - 512) * 1536;
            tt[ty + r * 8][tx] = s[n0 + tx];
        }
        __syncthreads();
#pragma unroll
        for (int r = 0; r < 4; ++r)
            Wcat_t[(size_t)(n0 + ty + r * 8) * 1024 + k0 + tx] = f2bf(tt[tx][ty + r * 8]);
        return;
    }
    if (blk < 14676) {  // K=512 transposes -> [N][512]
        const float* W; ushort* Wt; int idx, ncols;
        if (blk < 14292)      { idx = blk - 14036; W = Wfh; Wt = Wfh_t; ncols = 512; }
        else if (blk < 14548) { idx = blk - 14292; W = Wfx; Wt = Wfx_t; ncols = 512; }
        else                  { idx = blk - 14548; W = Wwh; Wt = Wwh_t; ncols = 256; }
        int nt_count = ncols >> 5;
        int k0 = (idx / nt_count) * 32, n0 = (idx % nt_count) * 32;
#pragma unroll
        for (int r = 0; r < 4; ++r)
            tt[ty + r * 8][tx] = W[(size_t)(k0 + ty + r * 8) * ncols + n0 + tx];
        __syncthreads();
#pragma unroll
        for (int r = 0; r < 4; ++r)
            Wt[(size_t)(n0 + ty + r * 8) * 512 + k0 + tx] = f2bf(tt[tx][ty + r * 8]);
        return;
    }
    {
        float s = 0.f;
        for (int o = 0; o < 30; ++o) s += Wwp[tid * 30 + o];
        wsum[tid] = s;
        if (tid == 0) {
            float t = 0.f;
            for (int o = 0; o < 30; ++o) t += bwp[o];
            wsum[256] = t;
        }
    }
}

// ---------------- mega gather (fp8 table, batch-loads-then-decode, R7-proven) ----------------
__global__ __launch_bounds__(256) void mega_gather_kernel(
    const int* __restrict__ q_v,
    const int* __restrict__ qa0, const int* __restrict__ na0,
    const int* __restrict__ qa1, const int* __restrict__ na1,
    const int* __restrict__ qa2, const int* __restrict__ na2,
    const int* __restrict__ query, const int* __restrict__ pos, const int* __restrict__ neg,
    const unsigned char* __restrict__ emb8,
    float* __restrict__ pools, ushort* __restrict__ Xleaf, ushort* __restrict__ XR) {
    __shared__ float sm[256][9];
    int tid = threadIdx.x;
    int c = tid & 63, g = tid >> 6;
    float acc[8] = {};
    if (blockIdx.x < 3584) {
        int s = blockIdx.x >> 9, b = blockIdx.x & 511;
        const int* aptr[7] = {q_v, qa0, na0, qa1, na1, qa2, na2};
        const int* ids = aptr[s] + b * 64 + g * 16;
        uint2 v[16];
#pragma unroll
        for (int t = 0; t < 16; ++t)
            v[t] = *(const uint2*)(emb8 + (size_t)ids[t] * 512 + c * 8);
#pragma unroll
        for (int t = 0; t < 16; ++t) { dec4_add(v[t].x, acc); dec4_add(v[t].y, acc + 4); }
#pragma unroll
        for (int k = 0; k < 8; ++k) sm[tid][k] = acc[k];
        __syncthreads();
        if (tid < 64) {
#pragma unroll
            for (int gg = 1; gg < 4; ++gg)
#pragma unroll
                for (int k = 0; k < 8; ++k) acc[k] += sm[tid + gg * 64][k];
            const float sc = 1.0f / (64.0f * FP8_SCALE);
            float* dst = pools + ((size_t)s * 512 + b) * 512 + tid * 8;
            *(float4*)dst = make_float4(acc[0] * sc, acc[1] * sc, acc[2] * sc, acc[3] * sc);
            *(float4*)(dst + 4) = make_float4(acc[4] * sc, acc[5] * sc, acc[6] * sc, acc[7] * sc);
        }
    } else {
        int idx = blockIdx.x - 3584;
        int t = idx >> 11, rem = idx & 2047, b = rem >> 2, node = rem & 3;
        const int* sptr[3] = {query, pos, neg};
        const int* ids = sptr[t] + b * 128 + node * 32 + g * 8;
        uint2 v[8];
#pragma unroll
        for (int k = 0; k < 8; ++k)
            v[k] = *(const uint2*)(emb8 + (size_t)ids[k] * 512 + c * 8);
#pragma unroll
        for (int k = 0; k < 8; ++k) { dec4_add(v[k].x, acc); dec4_add(v[k].y, acc + 4); }
#pragma unroll
        for (int k = 0; k < 8; ++k) sm[tid][k] = acc[k];
        __syncthreads();
        if (tid < 64) {
#pragma unroll
            for (int gg = 1; gg < 4; ++gg)
#pragma unroll
                for (int k = 0; k < 8; ++k) acc[k] += sm[tid + gg * 64][k];
            const float sc = 1.0f / (32.0f * FP8_SCALE);
            short8 o;
#pragma unroll
            for (int k = 0; k < 8; ++k) o[k] = (short)f2bf(acc[k] * sc);
            if (node < 3) {
                size_t r = ((size_t)(t * 512 + b)) * 3 + node;
                *(short8*)(Xleaf + r * 512 + tid * 8) = o;
            } else {
                size_t r = (size_t)(t * 512 + b);
                *(short8*)(XR + r * 1024 + tid * 8) = o;
            }
        }
    }
}

// ---------------- bf16 MFMA GEMM body (double-buffered, swizzled LDS) ----------------
__device__ inline void cstore(float* C, size_t idx, float v)  { C[idx] = v; }
__device__ inline void cstore(ushort* C, size_t idx, float v) { C[idx] = f2bf(v); }

template <typename OutT>
__device__ __forceinline__ void gemm_body(const ushort* __restrict__ A, int lda,
                                          const ushort* __restrict__ Bt, int ldb,
                                          OutT* __restrict__ C, int ldc, int K,
                                          int bx, int by, ushort* sA, ushort* sB) {
    int tid = threadIdx.x;
    int m0 = bx * 128, n0 = by * 128;
    int w = tid >> 6, lane = tid & 63;
    int wm = (w >> 1) * 64, wn = (w & 1) * 64;
    int l15 = lane & 15, g = lane >> 4;
    int srow = tid >> 2;
    int csw = (((tid & 3) ^ ((tid >> 3) & 3))) * 8;   // swizzled source chunk (elems)
    int crd = (g ^ ((l15 >> 1) & 3)) * 8;             // swizzled read chunk (elems)

    const ushort* Ag0 = A + (size_t)(m0 + srow) * lda + csw;
    const ushort* Ag1 = A + (size_t)(m0 + srow + 64) * lda + csw;
    const ushort* Bg0 = Bt + (size_t)(n0 + srow) * ldb + csw;
    const ushort* Bg1 = Bt + (size_t)(n0 + srow + 64) * ldb + csw;

    floatx4 acc[4][4] = {};

    auto stage = [&](int buf, int kb) {
        ushort* dA = sA + buf * 4096;
        ushort* dB = sB + buf * 4096;
        GLD16(Ag0 + kb, dA + w * 512);
        GLD16(Ag1 + kb, dA + 2048 + w * 512);
        GLD16(Bg0 + kb, dB + w * 512);
        GLD16(Bg1 + kb, dB + 2048 + w * 512);
    };

    stage(0, 0);
    __syncthreads();
    int cur = 0;
    for (int kb = 0; kb < K; kb += 32) {
        if (kb + 32 < K) stage(cur ^ 1, kb + 32);
        const ushort* bA = sA + cur * 4096;
        const ushort* bB = sB + cur * 4096;
        short8 af[4], bf[4];
#pragma unroll
        for (int f = 0; f < 4; ++f) {
            af[f] = *(const short8*)(bA + (wm + f * 16 + l15) * 32 + crd);
            bf[f] = *(const short8*)(bB + (wn + f * 16 + l15) * 32 + crd);
        }
#pragma unroll
        for (int i = 0; i < 4; ++i)
#pragma unroll
            for (int j = 0; j < 4; ++j)
                acc[i][j] = __builtin_amdgcn_mfma_f32_16x16x32_bf16(af[i], bf[j], acc[i][j], 0, 0, 0);
        __syncthreads();
        cur ^= 1;
    }
    // C/D layout (HW-verified): col = lane&15, row = 4*(lane>>4)+reg
#pragma unroll
    for (int i = 0; i < 4; ++i)
#pragma unroll
        for (int j = 0; j < 4; ++j) {
            int row = m0 + wm + i * 16 + g * 4;
            int col = n0 + wn + j * 16 + l15;
#pragma unroll
            for (int r = 0; r < 4; ++r)
                cstore(C, (size_t)(row + r) * ldc + col, acc[i][j][r]);
        }
}

// G1 (leaf IOU, 432 blocks) + dots (512 blocks) in one launch
__global__ __launch_bounds__(256) void g1_dots_kernel(
    const ushort* __restrict__ Xleaf, const ushort* __restrict__ Wcat_t,
    ushort* __restrict__ IOU_l,
    const float* __restrict__ pools, float* __restrict__ lossv) {
    __shared__ alignas(16) ushort sA[8192];
    __shared__ alignas(16) ushort sB[8192];
    __shared__ float red[6][4];
    int blk = blockIdx.x, tid = threadIdx.x;
    if (blk < 432) {
        gemm_body(Xleaf, 512, Wcat_t, 1024, IOU_l, 1536, 512, blk % 36, blk / 36, sA, sB);
        return;
    }
    int b = blk - 432;
    const float* pq = pools + (size_t)b * 512;
    float q0 = pq[tid], q1 = pq[tid + 256];
    float d[6];
#pragma unroll
    for (int a = 0; a < 6; ++a) {
        const float* pa = pools + ((size_t)(a + 1) * 512 + b) * 512;
        d[a] = q0 * pa[tid] + q1 * pa[tid + 256];
    }
    int lane = tid & 63, wid = tid >> 6;
#pragma unroll
    for (int a = 0; a < 6; ++a) {
        float v = d[a];
        for (int off = 32; off; off >>= 1) v += __shfl_down(v, off);
        if (lane == 0) red[a][wid] = v;
    }
    __syncthreads();
    if (tid == 0) {
        float l = 0.f;
#pragma unroll
        for (int i = 0; i < 3; ++i) {
            float dq = red[2*i][0] + red[2*i][1] + red[2*i][2] + red[2*i][3];
            float dn = red[2*i+1][0] + red[2*i+1][1] + red[2*i+1][2] + red[2*i+1][3];
            l += fmaxf(0.f, 1.f - dq + dn);
        }
        lossv[b] = l;
    }
}

// G4 (IOU_r, K=1024, blocks 0-143) + G2 (FH, 144-287) + G3 (FX, 288-335)
__global__ __launch_bounds__(256) void gemm3_kernel(
    const ushort* __restrict__ h_l, const ushort* __restrict__ XR,
    const ushort* __restrict__ Wfh_t, const ushort* __restrict__ Wfx_t,
    const ushort* __restrict__ Wcat_t,
    ushort* __restrict__ FH, ushort* __restrict__ FX, ushort* __restrict__ IOU_r) {
    __shared__ alignas(16) ushort sA[8192];
    __shared__ alignas(16) ushort sB[8192];
    int r = blockIdx.x;
    if (r < 144)      gemm_body(XR, 1024, Wcat_t, 1024, IOU_r, 1536, 1024, r % 12, r / 12, sA, sB);
    else if (r < 288) { int q = r - 144; gemm_body(h_l, 512, Wfh_t, 512, FH, 512, 512, q % 36, q / 36, sA, sB); }
    else              { int q = r - 288; gemm_body(XR, 1024, Wfx_t, 512, FX, 512, 512, q % 12, q / 12, sA, sB); }
}

// sim GEMM: S[1024,256] = P @ Wwh, P rows built on the fly from c_root.
__global__ __launch_bounds__(256) void gemm_sim_kernel(
    const float* __restrict__ c_root, const ushort* __restrict__ Wwh_t,
    float* __restrict__ S) {
    __shared__ alignas(16) ushort sA[8192];
    __shared__ alignas(16) ushort sB[8192];
    int tid = threadIdx.x;
    int bx = blockIdx.x & 7, by = blockIdx.x >> 3;
    int m0 = bx * 128, n0 = by * 128;
    int w = tid >> 6, lane = tid & 63;
    int wm = (w >> 1) * 64, wn = (w & 1) * 64;
    int l15 = lane & 15, g = lane >> 4;
    int srow = tid >> 2;
    int csw = (((tid & 3) ^ ((tid >> 3) & 3))) * 8;
    int crd = (g ^ ((l15 >> 1) & 3)) * 8;

    const ushort* Bg0 = Wwh_t + (size_t)(n0 + srow) * 512 + csw;
    const ushort* Bg1 = Wwh_t + (size_t)(n0 + srow + 64) * 512 + csw;

    floatx4 acc[4][4] = {};

    auto stage = [&](int buf, int kb) {
        ushort* dA = sA + buf * 4096;
        ushort* dB = sB + buf * 4096;
        GLD16(Bg0 + kb, dB + w * 512);
        GLD16(Bg1 + kb, dB + 2048 + w * 512);
#pragma unroll
        for (int half = 0; half < 2; ++half) {
            int gr = m0 + srow + half * 64;
            int b = gr & 511, which = gr >> 9;
            const float* qrow = c_root + (size_t)b * 512 + kb + csw;
            const float* orow = c_root + ((size_t)(which + 1) * 512 + b) * 512 + kb + csw;
            float4 q0 = *(const float4*)qrow, q1 = *(const float4*)(qrow + 4);
            float4 o0 = *(const float4*)orow, o1 = *(const float4*)(orow + 4);
            short8 pv;
            pv[0] = (short)f2bf(q0.x * o0.x); pv[1] = (short)f2bf(q0.y * o0.y);
            pv[2] = (short)f2bf(q0.z * o0.z); pv[3] = (short)f2bf(q0.w * o0.w);
            pv[4] = (short)f2bf(q1.x * o1.x); pv[5] = (short)f2bf(q1.y * o1.y);
            pv[6] = (short)f2bf(q1.z * o1.z); pv[7] = (short)f2bf(q1.w * o1.w);
            *(short8*)(dA + (srow + half * 64) * 32 + (tid & 3) * 8) = pv;
        }
    };

    stage(0, 0);
    __syncthreads();
    int cur = 0;
    for (int kb = 0; kb < 512; kb += 32) {
        if (kb + 32 < 512) stage(cur ^ 1, kb + 32);
        const ushort* bA = sA + cur * 4096;
        const ushort* bB = sB + cur * 4096;
        short8 af[4], bf[4];
#pragma unroll
        for (int f = 0; f < 4; ++f) {
            af[f] = *(const short8*)(bA + (wm + f * 16 + l15) * 32 + crd);
            bf[f] = *(const short8*)(bB + (wn + f * 16 + l15) * 32 + crd);
        }
#pragma unroll
        for (int i = 0; i < 4; ++i)
#pragma unroll
            for (int j = 0; j < 4; ++j)
                acc[i][j] = __builtin_amdgcn_mfma_f32_16x16x32_bf16(af[i], bf[j], acc[i][j], 0, 0, 0);
        __syncthreads();
        cur ^= 1;
    }
#pragma unroll
    for (int i = 0; i < 4; ++i)
#pragma unroll
        for (int j = 0; j < 4; ++j) {
            int row = m0 + wm + i * 16 + g * 4;
            int col = n0 + wn + j * 16 + l15;
#pragma unroll
            for (int r = 0; r < 4; ++r)
                S[(size_t)(row + r) * 256 + col] = acc[i][j][r];
        }
}

// ---------------- TreeLSTM epilogues (vectorized: 4 trees/block, 64 lanes/tree) ----------------

__global__ __launch_bounds__(256) void leaf_act_kernel(
    const ushort* __restrict__ IOU_l, const float* __restrict__ bioux,
    const float* __restrict__ biouh, ushort* __restrict__ c_l,
    ushort* __restrict__ h_l, ushort* __restrict__ XR) {
    int tb = blockIdx.x * 4 + (threadIdx.x >> 6);
    int d0 = (threadIdx.x & 63) * 8;
    float bi[8], bo[8], bu[8];
#pragma unroll
    for (int gate = 0; gate < 3; ++gate) {
        float* dst = gate == 0 ? bi : (gate == 1 ? bo : bu);
        int m = gate * 512 + d0;
        float4 x0 = *(const float4*)(bioux + m), x1 = *(const float4*)(bioux + m + 4);
        float4 h0 = *(const float4*)(biouh + m), h1 = *(const float4*)(biouh + m + 4);
        dst[0] = x0.x + h0.x; dst[1] = x0.y + h0.y; dst[2] = x0.z + h0.z; dst[3] = x0.w + h0.w;
        dst[4] = x1.x + h1.x; dst[5] = x1.y + h1.y; dst[6] = x1.z + h1.z; dst[7] = x1.w + h1.w;
    }
    float hs[8] = {};
#pragma unroll
    for (int leaf = 0; leaf < 3; ++leaf) {
        size_t r = (size_t)tb * 3 + leaf;
        short8 vi = *(const short8*)(IOU_l + r * 1536 + d0);
        short8 vo = *(const short8*)(IOU_l + r * 1536 + 512 + d0);
        short8 vu = *(const short8*)(IOU_l + r * 1536 + 1024 + d0);
        short8 cb, hb;
#pragma unroll
        for (int j = 0; j < 8; ++j) {
            float iv = sigm(bf2f((ushort)vi[j]) + bi[j]);
            float ov = sigm(bf2f((ushort)vo[j]) + bo[j]);
            float uv = tanhf(bf2f((ushort)vu[j]) + bu[j]);
            float cc = iv * uv;
            cb[j] = (short)f2bf(cc);
            float hh = ov * tanhf(cc);
            hb[j] = (short)f2bf(hh);
            hs[j] += hh;
        }
        *(short8*)(c_l + r * 512 + d0) = cb;
        *(short8*)(h_l + r * 512 + d0) = hb;
    }
    short8 hsb;
#pragma unroll
    for (int j = 0; j < 8; ++j) hsb[j] = (short)f2bf(hs[j]);
    *(short8*)(XR + (size_t)tb * 1024 + 512 + d0) = hsb;
}

__global__ __launch_bounds__(256) void root_act_kernel(
    const ushort* __restrict__ IOU_r, const ushort* __restrict__ FH,
    const ushort* __restrict__ FX, const ushort* __restrict__ c_l,
    const float* __restrict__ bioux, const float* __restrict__ biouh,
    const float* __restrict__ bfx, const float* __restrict__ bfh,
    float* __restrict__ c_root) {
    int r = blockIdx.x * 4 + (threadIdx.x >> 6);
    int d0 = (threadIdx.x & 63) * 8;
    float bi[8], bu[8], bfxv[8], bfhv[8];
    {
        float4 x0 = *(const float4*)(bioux + d0), x1 = *(const float4*)(bioux + d0 + 4);
        float4 h0 = *(const float4*)(biouh + d0), h1 = *(const float4*)(biouh + d0 + 4);
        bi[0] = x0.x + h0.x; bi[1] = x0.y + h0.y; bi[2] = x0.z + h0.z; bi[3] = x0.w + h0.w;
        bi[4] = x1.x + h1.x; bi[5] = x1.y + h1.y; bi[6] = x1.z + h1.z; bi[7] = x1.w + h1.w;
        float4 u0 = *(const float4*)(bioux + 1024 + d0), u1 = *(const float4*)(bioux + 1024 + d0 + 4);
        float4 v0 = *(const float4*)(biouh + 1024 + d0), v1 = *(const float4*)(biouh + 1024 + d0 + 4);
        bu[0] = u0.x + v0.x; bu[1] = u0.y + v0.y; bu[2] = u0.z + v0.z; bu[3] = u0.w + v0.w;
        bu[4] = u1.x + v1.x; bu[5] = u1.y + v1.y; bu[6] = u1.z + v1.z; bu[7] = u1.w + v1.w;
        float4 f0 = *(const float4*)(bfx + d0), f1 = *(const float4*)(bfx + d0 + 4);
        bfxv[0] = f0.x; bfxv[1] = f0.y; bfxv[2] = f0.z; bfxv[3] = f0.w;
        bfxv[4] = f1.x; bfxv[5] = f1.y; bfxv[6] = f1.z; bfxv[7] = f1.w;
        float4 g0 = *(const float4*)(bfh + d0), g1 = *(const float4*)(bfh + d0 + 4);
        bfhv[0] = g0.x; bfhv[1] = g0.y; bfhv[2] = g0.z; bfhv[3] = g0.w;
        bfhv[4] = g1.x; bfhv[5] = g1.y; bfhv[6] = g1.z; bfhv[7] = g1.w;
    }
    short8 vi = *(const short8*)(IOU_r + (size_t)r * 1536 + d0);
    short8 vu = *(const short8*)(IOU_r + (size_t)r * 1536 + 1024 + d0);
    short8 vfx = *(const short8*)(FX + (size_t)r * 512 + d0);
    float c[8], fx[8];
#pragma unroll
    for (int j = 0; j < 8; ++j) {
        float iv = sigm(bf2f((ushort)vi[j]) + bi[j]);
        float uv = tanhf(bf2f((ushort)vu[j]) + bu[j]);
        fx[j] = bf2f((ushort)vfx[j]) + bfxv[j];
        c[j] = iv * uv;
    }
#pragma unroll
    for (int k = 0; k < 3; ++k) {
        size_t rr = ((size_t)r * 3 + k) * 512 + d0;
        short8 vfh = *(const short8*)(FH + rr);
        short8 vcl = *(const short8*)(c_l + rr);
#pragma unroll
        for (int j = 0; j < 8; ++j) {
            float f = sigm(bf2f((ushort)vfh[j]) + bfhv[j] + fx[j]);
            c[j] += f * bf2f((ushort)vcl[j]);
        }
    }
    *(float4*)(c_root + (size_t)r * 512 + d0)     = make_float4(c[0], c[1], c[2], c[3]);
    *(float4*)(c_root + (size_t)r * 512 + d0 + 4) = make_float4(c[4], c[5], c[6], c[7]);
}

__global__ __launch_bounds__(256) void final_kernel(
    const float* __restrict__ S, const float* __restrict__ bwh,
    const float* __restrict__ wsum, const float* __restrict__ loss,
    float* __restrict__ out) {
    int b = blockIdx.x, tid = threadIdx.x;
    float w = wsum[tid];
    float bw = bwh[tid];
    float va = sigm(S[(size_t)b * 256 + tid] + bw) * w;
    float vb = sigm(S[(size_t)(512 + b) * 256 + tid] + bw) * w;
    int lane = tid & 63, wid = tid >> 6;
    for (int off = 32; off; off >>= 1) {
        va += __shfl_down(va, off);
        vb += __shfl_down(vb, off);
    }
    __shared__ float ra[4], rb[4];
    if (lane == 0) { ra[wid] = va; rb[wid] = vb; }
    __syncthreads();
    if (tid == 0) {
        float a  = ra[0] + ra[1] + ra[2] + ra[3] + wsum[256];
        float bb = rb[0] + rb[1] + rb[2] + rb[3] + wsum[256];
        out[b] = loss[b] + fmaxf(0.f, 1.f - a + bb);
    }
}

// ---------------- launch ----------------

extern "C" void kernel_launch(void* const* d_in, const int* in_sizes, int n_in,
                              void* d_out, int out_size, void* d_ws, size_t ws_size,
                              hipStream_t stream) {
    const int* q_v   = (const int*)d_in[0];
    const int* q_a0  = (const int*)d_in[1];
    const int* n_a0  = (const int*)d_in[2];
    const int* q_a1  = (const int*)d_in[3];
    const int* n_a1  = (const int*)d_in[4];
    const int* q_a2  = (const int*)d_in[5];
    const int* n_a2  = (const int*)d_in[6];
    const int* query = (const int*)d_in[7];
    const int* pos   = (const int*)d_in[8];
    const int* neg   = (const int*)d_in[9];
    const float* emb   = (const float*)d_in[10];
    const float* Wioux = (const float*)d_in[11];
    const float* bioux = (const float*)d_in[12];
    const float* Wiouh = (const float*)d_in[13];
    const float* biouh = (const float*)d_in[14];
    const float* Wfx   = (const float*)d_in[15];
    const float* bfx   = (const float*)d_in[16];
    const float* Wfh   = (const float*)d_in[17];
    const float* bfh   = (const float*)d_in[18];
    const float* Wwh   = (const float*)d_in[19];
    const float* bwh   = (const float*)d_in[20];
    const float* Wwp   = (const float*)d_in[21];
    const float* bwp   = (const float*)d_in[22];
    float* out = (float*)d_out;

    char* w = (char*)d_ws;
    size_t off = 0;
    auto alloc = [&](size_t bytes) -> void* {
        void* p = (void*)(w + off);
        off = (off + bytes + 255) & ~(size_t)255;
        return p;
    };
    // ---- persistent region ----
    ushort* Wcat_t = (ushort*)alloc((size_t)1536 * 1024 * 2);
    ushort* Wfh_t  = (ushort*)alloc((size_t)512 * 512 * 2);
    ushort* Wfx_t  = (ushort*)alloc((size_t)512 * 512 * 2);
    ushort* Wwh_t  = (ushort*)alloc((size_t)256 * 512 * 2);
    float*  wsum   = (float*) alloc(257 * 4);
    float*  lossv  = (float*) alloc(512 * 4);
    ushort* Xleaf  = (ushort*)alloc((size_t)4608 * 512 * 2);
    ushort* XR     = (ushort*)alloc((size_t)1536 * 1024 * 2);
    // ---- aliased region: phase1 (emb8, pools) then phase2 (GEMM temporaries) ----
    size_t xbase = off;
    unsigned char* emb8 = (unsigned char*)alloc((size_t)50000 * 512);
    float* pools        = (float*)        alloc((size_t)7 * 512 * 512 * 4);
    off = xbase;   // rewind: safe by ordering (emb8 dead after gather; pools dead after dots)
    ushort* IOU_l  = (ushort*)alloc((size_t)4608 * 1536 * 2);
    ushort* c_l    = (ushort*)alloc((size_t)4608 * 512 * 2);
    ushort* h_l    = (ushort*)alloc((size_t)4608 * 512 * 2);
    ushort* FH     = (ushort*)alloc((size_t)4608 * 512 * 2);
    ushort* FX     = (ushort*)alloc((size_t)1536 * 512 * 2);
    ushort* IOU_r  = (ushort*)alloc((size_t)1536 * 1536 * 2);
    float*  c_root = (float*) alloc((size_t)1536 * 512 * 4);
    float*  S      = (float*) alloc((size_t)1024 * 256 * 4);

    prep_all_kernel<<<14677, 256, 0, stream>>>(emb, emb8, Wioux, Wiouh, Wfh, Wfx, Wwh,
                                               Wwp, bwp, Wcat_t, Wfh_t, Wfx_t, Wwh_t, wsum);
    mega_gather_kernel<<<9728, 256, 0, stream>>>(q_v, q_a0, n_a0, q_a1, n_a1, q_a2, n_a2,
                                                 query, pos, neg, emb8, pools, Xleaf, XR);
    g1_dots_kernel<<<944, 256, 0, stream>>>(Xleaf, Wcat_t, IOU_l, pools, lossv);
    leaf_act_kernel<<<384, 256, 0, stream>>>(IOU_l, bioux, biouh, c_l, h_l, XR);
    gemm3_kernel<<<336, 256, 0, stream>>>(h_l, XR, Wfh_t, Wfx_t, Wcat_t, FH, FX, IOU_r);
    root_act_kernel<<<384, 256, 0, stream>>>(IOU_r, FH, FX, c_l, bioux, biouh, bfx, bfh, c_root);
    gemm_sim_kernel<<<16, 256, 0, stream>>>(c_root, Wwh_t, S);
    final_kernel<<<512, 256, 0, stream>>>(S, bwh, wsum, lossv, out);
}

// Round 10
// 126.795 us; speedup vs baseline: 1.0471x; 1.0048x over previous
//
#include <hip/hip_runtime.h>
#include <hip/hip_bf16.h>

// FEELModel: fp8 emb table + fused gathers (fp32 accum); TreeLSTM + sim head via bf16 MFMA.
// R10 = R9, with weight-prep blocks moved out of the conv->gather critical path:
// prep kernel = emb conversion only; transposes+wsum ride in the gather launch.
// B=512, L=64, Lq=128, D=M=512, 3M=1536, H=256, O=30

typedef __attribute__((ext_vector_type(8))) short short8;   // 8 bf16
typedef __attribute__((ext_vector_type(4))) float floatx4;  // MFMA C/D frag
typedef __attribute__((ext_vector_type(2))) float floatx2;

__device__ inline ushort f2bf(float f) {            // fp32 -> bf16 bits, RNE
    unsigned u = __float_as_uint(f);
    u += 0x7fffu + ((u >> 16) & 1u);
    return (ushort)(u >> 16);
}
__device__ inline float bf2f(ushort u) { return __uint_as_float((unsigned)u << 16); }
__device__ inline float sigm(float x) { return 1.0f / (1.0f + expf(-x)); }

#if defined(__has_builtin)
#if __has_builtin(__builtin_amdgcn_cvt_pk_f32_fp8) && __has_builtin(__builtin_amdgcn_cvt_pk_fp8_f32)
#define HW_FP8 1
#endif
#endif

#ifndef HW_FP8
__device__ inline unsigned enc1(float x) {          // manual e4m3fn encode, RNE, saturating
    float a = fabsf(x);
    unsigned s = (__float_as_uint(x) >> 31) << 7;
    unsigned b = __float_as_uint(a);
    unsigned uexp = b >> 23;
    if (uexp < 121) {
        int m = (int)(a * 512.0f + 0.5f);
        if (m >= 8) return s | 0x08u;
        return s | (unsigned)m;
    }
    b += 0x00080000u;
    unsigned e = b >> 23;
    if (e > 135u) return s | 0x7Eu;
    return s | ((e - 120u) << 3) | ((b >> 20) & 7u);
}
__device__ inline float dec1(unsigned v) {
    unsigned s = (v >> 7) & 1u, e = (v >> 3) & 15u, m = v & 7u;
    float r = e ? __uint_as_float(((e + 120u) << 23) | (m << 20))
                : (float)m * 0.001953125f;
    return s ? -r : r;
}
#endif

__device__ inline unsigned pk4(float a, float b, float c, float d) {
#ifdef HW_FP8
    int v = 0;
    v = __builtin_amdgcn_cvt_pk_fp8_f32(a, b, v, false);
    v = __builtin_amdgcn_cvt_pk_fp8_f32(c, d, v, true);
    return (unsigned)v;
#else
    return enc1(a) | (enc1(b) << 8) | (enc1(c) << 16) | (enc1(d) << 24);
#endif
}
__device__ inline void dec4_add(unsigned v, float* acc) {
#ifdef HW_FP8
    floatx2 p0 = __builtin_amdgcn_cvt_pk_f32_fp8(v, false);
    floatx2 p1 = __builtin_amdgcn_cvt_pk_f32_fp8(v, true);
    acc[0] += p0[0]; acc[1] += p0[1]; acc[2] += p1[0]; acc[3] += p1[1];
#else
    acc[0] += dec1(v & 255u); acc[1] += dec1((v >> 8) & 255u);
    acc[2] += dec1((v >> 16) & 255u); acc[3] += dec1(v >> 24);
#endif
}

#define GLD16(gp, sp)                                                        \
    __builtin_amdgcn_global_load_lds(                                        \
        (const __attribute__((address_space(1))) unsigned int*)(const void*)(gp), \
        (__attribute__((address_space(3))) unsigned int*)(void*)(sp), 16, 0, 0)

#define FP8_SCALE 64.0f

// ---------------- conv: emb fp32 -> fp8 (x64 scale), 8 elems/thread ----------------
__global__ __launch_bounds__(256) void conv_kernel(const float* __restrict__ emb,
                                                   unsigned char* __restrict__ emb8) {
    size_t i = ((size_t)blockIdx.x * 256 + threadIdx.x) * 8;
    float4 a = *(const float4*)(emb + i);
    float4 b = *(const float4*)(emb + i + 4);
    uint2 o;
    o.x = pk4(a.x * FP8_SCALE, a.y * FP8_SCALE, a.z * FP8_SCALE, a.w * FP8_SCALE);
    o.y = pk4(b.x * FP8_SCALE, b.y * FP8_SCALE, b.z * FP8_SCALE, b.w * FP8_SCALE);
    *(uint2*)(emb8 + i) = o;
}

// ---------------- mega gather (R7-proven internals) + weight prep tail ----------------
// blocks [0,3584): attr pools -> fp32 pools ; [3584,9728): tree pools -> Xleaf/XR
// blocks [9728,11905): weight transposes + wsum (independent of emb8; hide under gather)
__global__ __launch_bounds__(256) void mega_gather_kernel(
    const int* __restrict__ q_v,
    const int* __restrict__ qa0, const int* __restrict__ na0,
    const int* __restrict__ qa1, const int* __restrict__ na1,
    const int* __restrict__ qa2, const int* __restrict__ na2,
    const int* __restrict__ query, const int* __restrict__ pos, const int* __restrict__ neg,
    const unsigned char* __restrict__ emb8,
    float* __restrict__ pools, ushort* __restrict__ Xleaf, ushort* __restrict__ XR,
    const float* __restrict__ Wioux, const float* __restrict__ Wiouh,
    const float* __restrict__ Wfh, const float* __restrict__ Wfx,
    const float* __restrict__ Wwh, const float* __restrict__ Wwp,
    const float* __restrict__ bwp,
    ushort* __restrict__ Wcat_t, ushort* __restrict__ Wfh_t,
    ushort* __restrict__ Wfx_t, ushort* __restrict__ Wwh_t,
    float* __restrict__ wsum) {
    __shared__ alignas(16) char smem_u[9216];
    int tid = threadIdx.x;

    if (blockIdx.x < 9728) {   // ---- gather (identical to R7/R9) ----
        float (*sm)[9] = (float(*)[9])smem_u;
        int c = tid & 63, g = tid >> 6;
        float acc[8] = {};
        if (blockIdx.x < 3584) {
            int s = blockIdx.x >> 9, b = blockIdx.x & 511;
            const int* aptr[7] = {q_v, qa0, na0, qa1, na1, qa2, na2};
            const int* ids = aptr[s] + b * 64 + g * 16;
            uint2 v[16];
#pragma unroll
            for (int t = 0; t < 16; ++t)
                v[t] = *(const uint2*)(emb8 + (size_t)ids[t] * 512 + c * 8);
#pragma unroll
            for (int t = 0; t < 16; ++t) { dec4_add(v[t].x, acc); dec4_add(v[t].y, acc + 4); }
#pragma unroll
            for (int k = 0; k < 8; ++k) sm[tid][k] = acc[k];
            __syncthreads();
            if (tid < 64) {
#pragma unroll
                for (int gg = 1; gg < 4; ++gg)
#pragma unroll
                    for (int k = 0; k < 8; ++k) acc[k] += sm[tid + gg * 64][k];
                const float sc = 1.0f / (64.0f * FP8_SCALE);
                float* dst = pools + ((size_t)s * 512 + b) * 512 + tid * 8;
                *(float4*)dst = make_float4(acc[0] * sc, acc[1] * sc, acc[2] * sc, acc[3] * sc);
                *(float4*)(dst + 4) = make_float4(acc[4] * sc, acc[5] * sc, acc[6] * sc, acc[7] * sc);
            }
        } else {
            int idx = blockIdx.x - 3584;
            int t = idx >> 11, rem = idx & 2047, b = rem >> 2, node = rem & 3;
            const int* sptr[3] = {query, pos, neg};
            const int* ids = sptr[t] + b * 128 + node * 32 + g * 8;
            uint2 v[8];
#pragma unroll
            for (int k = 0; k < 8; ++k)
                v[k] = *(const uint2*)(emb8 + (size_t)ids[k] * 512 + c * 8);
#pragma unroll
            for (int k = 0; k < 8; ++k) { dec4_add(v[k].x, acc); dec4_add(v[k].y, acc + 4); }
#pragma unroll
            for (int k = 0; k < 8; ++k) sm[tid][k] = acc[k];
            __syncthreads();
            if (tid < 64) {
#pragma unroll
                for (int gg = 1; gg < 4; ++gg)
#pragma unroll
                    for (int k = 0; k < 8; ++k) acc[k] += sm[tid + gg * 64][k];
                const float sc = 1.0f / (32.0f * FP8_SCALE);
                short8 o;
#pragma unroll
                for (int k = 0; k < 8; ++k) o[k] = (short)f2bf(acc[k] * sc);
                if (node < 3) {
                    size_t r = ((size_t)(t * 512 + b)) * 3 + node;
                    *(short8*)(Xleaf + r * 512 + tid * 8) = o;
                } else {
                    size_t r = (size_t)(t * 512 + b);
                    *(short8*)(XR + r * 1024 + tid * 8) = o;
                }
            }
        }
        return;
    }
    // ---- weight prep (coalesced LDS transposes) ----
    float* tt = (float*)smem_u;                 // [32][33]
    int wblk = blockIdx.x - 9728;
    int tx = tid & 31, ty = tid >> 5;
    if (wblk < 1536) {  // Wcat: logical [1024][1536] -> Wcat_t[1536][1024]
        int k0 = (wblk & 31) * 32, n0 = (wblk >> 5) * 32;
#pragma unroll
        for (int r = 0; r < 4; ++r) {
            int k = k0 + ty + r * 8;
            const float* s = (k < 512) ? Wioux + (size_t)k * 1536
                                       : Wiouh + (size_t)(k - 512) * 1536;
            tt[(ty + r * 8) * 33 + tx] = s[n0 + tx];
        }
        __syncthreads();
#pragma unroll
        for (int r = 0; r < 4; ++r)
            Wcat_t[(size_t)(n0 + ty + r * 8) * 1024 + k0 + tx] = f2bf(tt[tx * 33 + ty + r * 8]);
        return;
    }
    if (wblk < 2176) {  // K=512 transposes -> [N][512]
        const float* W; ushort* Wt; int idx, ncols;
        if (wblk < 1792)      { idx = wblk - 1536; W = Wfh; Wt = Wfh_t; ncols = 512; }
        else if (wblk < 2048) { idx = wblk - 1792; W = Wfx; Wt = Wfx_t; ncols = 512; }
        else                  { idx = wblk - 2048; W = Wwh; Wt = Wwh_t; ncols = 256; }
        int nt_count = ncols >> 5;
        int k0 = (idx / nt_count) * 32, n0 = (idx % nt_count) * 32;
#pragma unroll
        for (int r = 0; r < 4; ++r)
            tt[(ty + r * 8) * 33 + tx] = W[(size_t)(k0 + ty + r * 8) * ncols + n0 + tx];
        __syncthreads();
#pragma unroll
        for (int r = 0; r < 4; ++r)
            Wt[(size_t)(n0 + ty + r * 8) * 512 + k0 + tx] = f2bf(tt[tx * 33 + ty + r * 8]);
        return;
    }
    {   // wsum
        float s = 0.f;
        for (int o = 0; o < 30; ++o) s += Wwp[tid * 30 + o];
        wsum[tid] = s;
        if (tid == 0) {
            float t = 0.f;
            for (int o = 0; o < 30; ++o) t += bwp[o];
            wsum[256] = t;
        }
    }
}

// ---------------- bf16 MFMA GEMM body (double-buffered, swizzled LDS) ----------------
__device__ inline void cstore(float* C, size_t idx, float v)  { C[idx] = v; }
__device__ inline void cstore(ushort* C, size_t idx, float v) { C[idx] = f2bf(v); }

template <typename OutT>
__device__ __forceinline__ void gemm_body(const ushort* __restrict__ A, int lda,
                                          const ushort* __restrict__ Bt, int ldb,
                                          OutT* __restrict__ C, int ldc, int K,
                                          int bx, int by, ushort* sA, ushort* sB) {
    int tid = threadIdx.x;
    int m0 = bx * 128, n0 = by * 128;
    int w = tid >> 6, lane = tid & 63;
    int wm = (w >> 1) * 64, wn = (w & 1) * 64;
    int l15 = lane & 15, g = lane >> 4;
    int srow = tid >> 2;
    int csw = (((tid & 3) ^ ((tid >> 3) & 3))) * 8;   // swizzled source chunk (elems)
    int crd = (g ^ ((l15 >> 1) & 3)) * 8;             // swizzled read chunk (elems)

    const ushort* Ag0 = A + (size_t)(m0 + srow) * lda + csw;
    const ushort* Ag1 = A + (size_t)(m0 + srow + 64) * lda + csw;
    const ushort* Bg0 = Bt + (size_t)(n0 + srow) * ldb + csw;
    const ushort* Bg1 = Bt + (size_t)(n0 + srow + 64) * ldb + csw;

    floatx4 acc[4][4] = {};

    auto stage = [&](int buf, int kb) {
        ushort* dA = sA + buf * 4096;
        ushort* dB = sB + buf * 4096;
        GLD16(Ag0 + kb, dA + w * 512);
        GLD16(Ag1 + kb, dA + 2048 + w * 512);
        GLD16(Bg0 + kb, dB + w * 512);
        GLD16(Bg1 + kb, dB + 2048 + w * 512);
    };

    stage(0, 0);
    __syncthreads();
    int cur = 0;
    for (int kb = 0; kb < K; kb += 32) {
        if (kb + 32 < K) stage(cur ^ 1, kb + 32);
        const ushort* bA = sA + cur * 4096;
        const ushort* bB = sB + cur * 4096;
        short8 af[4], bf[4];
#pragma unroll
        for (int f = 0; f < 4; ++f) {
            af[f] = *(const short8*)(bA + (wm + f * 16 + l15) * 32 + crd);
            bf[f] = *(const short8*)(bB + (wn + f * 16 + l15) * 32 + crd);
        }
#pragma unroll
        for (int i = 0; i < 4; ++i)
#pragma unroll
            for (int j = 0; j < 4; ++j)
                acc[i][j] = __builtin_amdgcn_mfma_f32_16x16x32_bf16(af[i], bf[j], acc[i][j], 0, 0, 0);
        __syncthreads();
        cur ^= 1;
    }
    // C/D layout (HW-verified): col = lane&15, row = 4*(lane>>4)+reg
#pragma unroll
    for (int i = 0; i < 4; ++i)
#pragma unroll
        for (int j = 0; j < 4; ++j) {
            int row = m0 + wm + i * 16 + g * 4;
            int col = n0 + wn + j * 16 + l15;
#pragma unroll
            for (int r = 0; r < 4; ++r)
                cstore(C, (size_t)(row + r) * ldc + col, acc[i][j][r]);
        }
}

// G1 (leaf IOU, 432 blocks) + dots (512 blocks) in one launch
__global__ __launch_bounds__(256) void g1_dots_kernel(
    const ushort* __restrict__ Xleaf, const ushort* __restrict__ Wcat_t,
    ushort* __restrict__ IOU_l,
    const float* __restrict__ pools, float* __restrict__ lossv) {
    __shared__ alignas(16) ushort sA[8192];
    __shared__ alignas(16) ushort sB[8192];
    __shared__ float red[6][4];
    int blk = blockIdx.x, tid = threadIdx.x;
    if (blk < 432) {
        gemm_body(Xleaf, 512, Wcat_t, 1024, IOU_l, 1536, 512, blk % 36, blk / 36, sA, sB);
        return;
    }
    int b = blk - 432;
    const float* pq = pools + (size_t)b * 512;
    float q0 = pq[tid], q1 = pq[tid + 256];
    float d[6];
#pragma unroll
    for (int a = 0; a < 6; ++a) {
        const float* pa = pools + ((size_t)(a + 1) * 512 + b) * 512;
        d[a] = q0 * pa[tid] + q1 * pa[tid + 256];
    }
    int lane = tid & 63, wid = tid >> 6;
#pragma unroll
    for (int a = 0; a < 6; ++a) {
        float v = d[a];
        for (int off = 32; off; off >>= 1) v += __shfl_down(v, off);
        if (lane == 0) red[a][wid] = v;
    }
    __syncthreads();
    if (tid == 0) {
        float l = 0.f;
#pragma unroll
        for (int i = 0; i < 3; ++i) {
            float dq = red[2*i][0] + red[2*i][1] + red[2*i][2] + red[2*i][3];
            float dn = red[2*i+1][0] + red[2*i+1][1] + red[2*i+1][2] + red[2*i+1][3];
            l += fmaxf(0.f, 1.f - dq + dn);
        }
        lossv[b] = l;
    }
}

// G4 (IOU_r, K=1024, blocks 0-143) + G2 (FH, 144-287) + G3 (FX, 288-335)
__global__ __launch_bounds__(256) void gemm3_kernel(
    const ushort* __restrict__ h_l, const ushort* __restrict__ XR,
    const ushort* __restrict__ Wfh_t, const ushort* __restrict__ Wfx_t,
    const ushort* __restrict__ Wcat_t,
    ushort* __restrict__ FH, ushort* __restrict__ FX, ushort* __restrict__ IOU_r) {
    __shared__ alignas(16) ushort sA[8192];
    __shared__ alignas(16) ushort sB[8192];
    int r = blockIdx.x;
    if (r < 144)      gemm_body(XR, 1024, Wcat_t, 1024, IOU_r, 1536, 1024, r % 12, r / 12, sA, sB);
    else if (r < 288) { int q = r - 144; gemm_body(h_l, 512, Wfh_t, 512, FH, 512, 512, q % 36, q / 36, sA, sB); }
    else              { int q = r - 288; gemm_body(XR, 1024, Wfx_t, 512, FX, 512, 512, q % 12, q / 12, sA, sB); }
}

// sim GEMM: S[1024,256] = P @ Wwh, P rows built on the fly from c_root.
__global__ __launch_bounds__(256) void gemm_sim_kernel(
    const float* __restrict__ c_root, const ushort* __restrict__ Wwh_t,
    float* __restrict__ S) {
    __shared__ alignas(16) ushort sA[8192];
    __shared__ alignas(16) ushort sB[8192];
    int tid = threadIdx.x;
    int bx = blockIdx.x & 7, by = blockIdx.x >> 3;
    int m0 = bx * 128, n0 = by * 128;
    int w = tid >> 6, lane = tid & 63;
    int wm = (w >> 1) * 64, wn = (w & 1) * 64;
    int l15 = lane & 15, g = lane >> 4;
    int srow = tid >> 2;
    int csw = (((tid & 3) ^ ((tid >> 3) & 3))) * 8;
    int crd = (g ^ ((l15 >> 1) & 3)) * 8;

    const ushort* Bg0 = Wwh_t + (size_t)(n0 + srow) * 512 + csw;
    const ushort* Bg1 = Wwh_t + (size_t)(n0 + srow + 64) * 512 + csw;

    floatx4 acc[4][4] = {};

    auto stage = [&](int buf, int kb) {
        ushort* dA = sA + buf * 4096;
        ushort* dB = sB + buf * 4096;
        GLD16(Bg0 + kb, dB + w * 512);
        GLD16(Bg1 + kb, dB + 2048 + w * 512);
#pragma unroll
        for (int half = 0; half < 2; ++half) {
            int gr = m0 + srow + half * 64;
            int b = gr & 511, which = gr >> 9;
            const float* qrow = c_root + (size_t)b * 512 + kb + csw;
            const float* orow = c_root + ((size_t)(which + 1) * 512 + b) * 512 + kb + csw;
            float4 q0 = *(const float4*)qrow, q1 = *(const float4*)(qrow + 4);
            float4 o0 = *(const float4*)orow, o1 = *(const float4*)(orow + 4);
            short8 pv;
            pv[0] = (short)f2bf(q0.x * o0.x); pv[1] = (short)f2bf(q0.y * o0.y);
            pv[2] = (short)f2bf(q0.z * o0.z); pv[3] = (short)f2bf(q0.w * o0.w);
            pv[4] = (short)f2bf(q1.x * o1.x); pv[5] = (short)f2bf(q1.y * o1.y);
            pv[6] = (short)f2bf(q1.z * o1.z); pv[7] = (short)f2bf(q1.w * o1.w);
            *(short8*)(dA + (srow + half * 64) * 32 + (tid & 3) * 8) = pv;
        }
    };

    stage(0, 0);
    __syncthreads();
    int cur = 0;
    for (int kb = 0; kb < 512; kb += 32) {
        if (kb + 32 < 512) stage(cur ^ 1, kb + 32);
        const ushort* bA = sA + cur * 4096;
        const ushort* bB = sB + cur * 4096;
        short8 af[4], bf[4];
#pragma unroll
        for (int f = 0; f < 4; ++f) {
            af[f] = *(const short8*)(bA + (wm + f * 16 + l15) * 32 + crd);
            bf[f] = *(const short8*)(bB + (wn + f * 16 + l15) * 32 + crd);
        }
#pragma unroll
        for (int i = 0; i < 4; ++i)
#pragma unroll
            for (int j = 0; j < 4; ++j)
                acc[i][j] = __builtin_amdgcn_mfma_f32_16x16x32_bf16(af[i], bf[j], acc[i][j], 0, 0, 0);
        __syncthreads();
        cur ^= 1;
    }
#pragma unroll
    for (int i = 0; i < 4; ++i)
#pragma unroll
        for (int j = 0; j < 4; ++j) {
            int row = m0 + wm + i * 16 + g * 4;
            int col = n0 + wn + j * 16 + l15;
#pragma unroll
            for (int r = 0; r < 4; ++r)
                S[(size_t)(row + r) * 256 + col] = acc[i][j][r];
        }
}

// ---------------- TreeLSTM epilogues (vectorized: 4 trees/block, 64 lanes/tree) ----------------

__global__ __launch_bounds__(256) void leaf_act_kernel(
    const ushort* __restrict__ IOU_l, const float* __restrict__ bioux,
    const float* __restrict__ biouh, ushort* __restrict__ c_l,
    ushort* __restrict__ h_l, ushort* __restrict__ XR) {
    int tb = blockIdx.x * 4 + (threadIdx.x >> 6);
    int d0 = (threadIdx.x & 63) * 8;
    float bi[8], bo[8], bu[8];
#pragma unroll
    for (int gate = 0; gate < 3; ++gate) {
        float* dst = gate == 0 ? bi : (gate == 1 ? bo : bu);
        int m = gate * 512 + d0;
        float4 x0 = *(const float4*)(bioux + m), x1 = *(const float4*)(bioux + m + 4);
        float4 h0 = *(const float4*)(biouh + m), h1 = *(const float4*)(biouh + m + 4);
        dst[0] = x0.x + h0.x; dst[1] = x0.y + h0.y; dst[2] = x0.z + h0.z; dst[3] = x0.w + h0.w;
        dst[4] = x1.x + h1.x; dst[5] = x1.y + h1.y; dst[6] = x1.z + h1.z; dst[7] = x1.w + h1.w;
    }
    float hs[8] = {};
#pragma unroll
    for (int leaf = 0; leaf < 3; ++leaf) {
        size_t r = (size_t)tb * 3 + leaf;
        short8 vi = *(const short8*)(IOU_l + r * 1536 + d0);
        short8 vo = *(const short8*)(IOU_l + r * 1536 + 512 + d0);
        short8 vu = *(const short8*)(IOU_l + r * 1536 + 1024 + d0);
        short8 cb, hb;
#pragma unroll
        for (int j = 0; j < 8; ++j) {
            float iv = sigm(bf2f((ushort)vi[j]) + bi[j]);
            float ov = sigm(bf2f((ushort)vo[j]) + bo[j]);
            float uv = tanhf(bf2f((ushort)vu[j]) + bu[j]);
            float cc = iv * uv;
            cb[j] = (short)f2bf(cc);
            float hh = ov * tanhf(cc);
            hb[j] = (short)f2bf(hh);
            hs[j] += hh;
        }
        *(short8*)(c_l + r * 512 + d0) = cb;
        *(short8*)(h_l + r * 512 + d0) = hb;
    }
    short8 hsb;
#pragma unroll
    for (int j = 0; j < 8; ++j) hsb[j] = (short)f2bf(hs[j]);
    *(short8*)(XR + (size_t)tb * 1024 + 512 + d0) = hsb;
}

__global__ __launch_bounds__(256) void root_act_kernel(
    const ushort* __restrict__ IOU_r, const ushort* __restrict__ FH,
    const ushort* __restrict__ FX, const ushort* __restrict__ c_l,
    const float* __restrict__ bioux, const float* __restrict__ biouh,
    const float* __restrict__ bfx, const float* __restrict__ bfh,
    float* __restrict__ c_root) {
    int r = blockIdx.x * 4 + (threadIdx.x >> 6);
    int d0 = (threadIdx.x & 63) * 8;
    float bi[8], bu[8], bfxv[8], bfhv[8];
    {
        float4 x0 = *(const float4*)(bioux + d0), x1 = *(const float4*)(bioux + d0 + 4);
        float4 h0 = *(const float4*)(biouh + d0), h1 = *(const float4*)(biouh + d0 + 4);
        bi[0] = x0.x + h0.x; bi[1] = x0.y + h0.y; bi[2] = x0.z + h0.z; bi[3] = x0.w + h0.w;
        bi[4] = x1.x + h1.x; bi[5] = x1.y + h1.y; bi[6] = x1.z + h1.z; bi[7] = x1.w + h1.w;
        float4 u0 = *(const float4*)(bioux + 1024 + d0), u1 = *(const float4*)(bioux + 1024 + d0 + 4);
        float4 v0 = *(const float4*)(biouh + 1024 + d0), v1 = *(const float4*)(biouh + 1024 + d0 + 4);
        bu[0] = u0.x + v0.x; bu[1] = u0.y + v0.y; bu[2] = u0.z + v0.z; bu[3] = u0.w + v0.w;
        bu[4] = u1.x + v1.x; bu[5] = u1.y + v1.y; bu[6] = u1.z + v1.z; bu[7] = u1.w + v1.w;
        float4 f0 = *(const float4*)(bfx + d0), f1 = *(const float4*)(bfx + d0 + 4);
        bfxv[0] = f0.x; bfxv[1] = f0.y; bfxv[2] = f0.z; bfxv[3] = f0.w;
        bfxv[4] = f1.x; bfxv[5] = f1.y; bfxv[6] = f1.z; bfxv[7] = f1.w;
        float4 g0 = *(const float4*)(bfh + d0), g1 = *(const float4*)(bfh + d0 + 4);
        bfhv[0] = g0.x; bfhv[1] = g0.y; bfhv[2] = g0.z; bfhv[3] = g0.w;
        bfhv[4] = g1.x; bfhv[5] = g1.y; bfhv[6] = g1.z; bfhv[7] = g1.w;
    }
    short8 vi = *(const short8*)(IOU_r + (size_t)r * 1536 + d0);
    short8 vu = *(const short8*)(IOU_r + (size_t)r * 1536 + 1024 + d0);
    short8 vfx = *(const short8*)(FX + (size_t)r * 512 + d0);
    float c[8], fx[8];
#pragma unroll
    for (int j = 0; j < 8; ++j) {
        float iv = sigm(bf2f((ushort)vi[j]) + bi[j]);
        float uv = tanhf(bf2f((ushort)vu[j]) + bu[j]);
        fx[j] = bf2f((ushort)vfx[j]) + bfxv[j];
        c[j] = iv * uv;
    }
#pragma unroll
    for (int k = 0; k < 3; ++k) {
        size_t rr = ((size_t)r * 3 + k) * 512 + d0;
        short8 vfh = *(const short8*)(FH + rr);
        short8 vcl = *(const short8*)(c_l + rr);
#pragma unroll
        for (int j = 0; j < 8; ++j) {
            float f = sigm(bf2f((ushort)vfh[j]) + bfhv[j] + fx[j]);
            c[j] += f * bf2f((ushort)vcl[j]);
        }
    }
    *(float4*)(c_root + (size_t)r * 512 + d0)     = make_float4(c[0], c[1], c[2], c[3]);
    *(float4*)(c_root + (size_t)r * 512 + d0 + 4) = make_float4(c[4], c[5], c[6], c[7]);
}

__global__ __launch_bounds__(256) void final_kernel(
    const float* __restrict__ S, const float* __restrict__ bwh,
    const float* __restrict__ wsum, const float* __restrict__ loss,
    float* __restrict__ out) {
    int b = blockIdx.x, tid = threadIdx.x;
    float w = wsum[tid];
    float bw = bwh[tid];
    float va = sigm(S[(size_t)b * 256 + tid] + bw) * w;
    float vb = sigm(S[(size_t)(512 + b) * 256 + tid] + bw) * w;
    int lane = tid & 63, wid = tid >> 6;
    for (int off = 32; off; off >>= 1) {
        va += __shfl_down(va, off);
        vb += __shfl_down(vb, off);
    }
    __shared__ float ra[4], rb[4];
    if (lane == 0) { ra[wid] = va; rb[wid] = vb; }
    __syncthreads();
    if (tid == 0) {
        float a  = ra[0] + ra[1] + ra[2] + ra[3] + wsum[256];
        float bb = rb[0] + rb[1] + rb[2] + rb[3] + wsum[256];
        out[b] = loss[b] + fmaxf(0.f, 1.f - a + bb);
    }
}

// ---------------- launch ----------------

extern "C" void kernel_launch(void* const* d_in, const int* in_sizes, int n_in,
                              void* d_out, int out_size, void* d_ws, size_t ws_size,
                              hipStream_t stream) {
    const int* q_v   = (const int*)d_in[0];
    const int* q_a0  = (const int*)d_in[1];
    const int* n_a0  = (const int*)d_in[2];
    const int* q_a1  = (const int*)d_in[3];
    const int* n_a1  = (const int*)d_in[4];
    const int* q_a2  = (const int*)d_in[5];
    const int* n_a2  = (const int*)d_in[6];
    const int* query = (const int*)d_in[7];
    const int* pos   = (const int*)d_in[8];
    const int* neg   = (const int*)d_in[9];
    const float* emb   = (const float*)d_in[10];
    const float* Wioux = (const float*)d_in[11];
    const float* bioux = (const float*)d_in[12];
    const float* Wiouh = (const float*)d_in[13];
    const float* biouh = (const float*)d_in[14];
    const float* Wfx   = (const float*)d_in[15];
    const float* bfx   = (const float*)d_in[16];
    const float* Wfh   = (const float*)d_in[17];
    const float* bfh   = (const float*)d_in[18];
    const float* Wwh   = (const float*)d_in[19];
    const float* bwh   = (const float*)d_in[20];
    const float* Wwp   = (const float*)d_in[21];
    const float* bwp   = (const float*)d_in[22];
    float* out = (float*)d_out;

    char* w = (char*)d_ws;
    size_t off = 0;
    auto alloc = [&](size_t bytes) -> void* {
        void* p = (void*)(w + off);
        off = (off + bytes + 255) & ~(size_t)255;
        return p;
    };
    // ---- persistent region ----
    ushort* Wcat_t = (ushort*)alloc((size_t)1536 * 1024 * 2);
    ushort* Wfh_t  = (ushort*)alloc((size_t)512 * 512 * 2);
    ushort* Wfx_t  = (ushort*)alloc((size_t)512 * 512 * 2);
    ushort* Wwh_t  = (ushort*)alloc((size_t)256 * 512 * 2);
    float*  wsum   = (float*) alloc(257 * 4);
    float*  lossv  = (float*) alloc(512 * 4);
    ushort* Xleaf  = (ushort*)alloc((size_t)4608 * 512 * 2);
    ushort* XR     = (ushort*)alloc((size_t)1536 * 1024 * 2);
    // ---- aliased region: phase1 (emb8, pools) then phase2 (GEMM temporaries) ----
    size_t xbase = off;
    unsigned char* emb8 = (unsigned char*)alloc((size_t)50000 * 512);
    float* pools        = (float*)        alloc((size_t)7 * 512 * 512 * 4);
    off = xbase;   // rewind: safe by ordering (emb8 dead after gather; pools dead after dots)
    ushort* IOU_l  = (ushort*)alloc((size_t)4608 * 1536 * 2);
    ushort* c_l    = (ushort*)alloc((size_t)4608 * 512 * 2);
    ushort* h_l    = (ushort*)alloc((size_t)4608 * 512 * 2);
    ushort* FH     = (ushort*)alloc((size_t)4608 * 512 * 2);
    ushort* FX     = (ushort*)alloc((size_t)1536 * 512 * 2);
    ushort* IOU_r  = (ushort*)alloc((size_t)1536 * 1536 * 2);
    float*  c_root = (float*) alloc((size_t)1536 * 512 * 4);
    float*  S      = (float*) alloc((size_t)1024 * 256 * 4);

    conv_kernel<<<12500, 256, 0, stream>>>(emb, emb8);
    mega_gather_kernel<<<11905, 256, 0, stream>>>(q_v, q_a0, n_a0, q_a1, n_a1, q_a2, n_a2,
                                                  query, pos, neg, emb8, pools, Xleaf, XR,
                                                  Wioux, Wiouh, Wfh, Wfx, Wwh, Wwp, bwp,
                                                  Wcat_t, Wfh_t, Wfx_t, Wwh_t, wsum);
    g1_dots_kernel<<<944, 256, 0, stream>>>(Xleaf, Wcat_t, IOU_l, pools, lossv);
    leaf_act_kernel<<<384, 256, 0, stream>>>(IOU_l, bioux, biouh, c_l, h_l, XR);
    gemm3_kernel<<<336, 256, 0, stream>>>(h_l, XR, Wfh_t, Wfx_t, Wcat_t, FH, FX, IOU_r);
    root_act_kernel<<<384, 256, 0, stream>>>(IOU_r, FH, FX, c_l, bioux, biouh, bfx, bfh, c_root);
    gemm_sim_kernel<<<16, 256, 0, stream>>>(c_root, Wwh_t, S);
    final_kernel<<<512, 256, 0, stream>>>(S, bwh, wsum, lossv, out);
}